// Round 1
// baseline (87.831 us; speedup 1.0000x reference)
//
#include <hip/hip_runtime.h>
#include <math.h>

// AdaptiveTemp: out[b] = delta_b / (EPS * sqrt(norm1*norminf)) with
// G = rho^2 * (dY/dlogits) (W^T W) (dY/dlogits)^T  -- no [M,D] Jacobian needed.
//
// C=10 classes, M=9, D=3072, B=2048.
// ws layout (floats): [0, 30720) = W_T [10][3072] ; [30720, 30820) = WtW [10][10]

#define NCLS 10
#define DIMD 3072
#define NSTAB 1e-7f
#define EPSI 0.1f

__global__ __launch_bounds__(256) void prep_kernel(const float* __restrict__ W,
                                                   float* __restrict__ ws) {
    const int tid = threadIdx.x;
    float* wt  = ws;               // W_T [10][3072]
    float* wtw = ws + NCLS * DIMD; // [10][10]

    if (blockIdx.x < 32) {
        // Transpose W [3072][10] -> W_T [10][3072] (coalesced writes)
        for (int idx = blockIdx.x * 256 + tid; idx < NCLS * DIMD; idx += 32 * 256) {
            int c = idx / DIMD;
            int d = idx - c * DIMD;
            wt[idx] = W[d * NCLS + c];
        }
    } else {
        // WtW = W^T W (upper triangle, 55 accumulators)
        float acc[55];
        #pragma unroll
        for (int i = 0; i < 55; i++) acc[i] = 0.f;
        for (int d = tid; d < DIMD; d += 256) {
            float w[NCLS];
            #pragma unroll
            for (int c = 0; c < NCLS; c++) w[c] = W[d * NCLS + c];
            int idx = 0;
            #pragma unroll
            for (int c1 = 0; c1 < NCLS; c1++) {
                #pragma unroll
                for (int c2 = c1; c2 < NCLS; c2++) {
                    acc[idx] = fmaf(w[c1], w[c2], acc[idx]);
                    idx++;
                }
            }
        }
        // wave butterfly reduce
        #pragma unroll
        for (int i = 0; i < 55; i++) {
            #pragma unroll
            for (int st = 1; st < 64; st <<= 1)
                acc[i] += __shfl_xor(acc[i], st, 64);
        }
        __shared__ float red[4 * 55];
        const int wv = tid >> 6, ln = tid & 63;
        if (ln == 0) {
            #pragma unroll
            for (int i = 0; i < 55; i++) red[wv * 55 + i] = acc[i];
        }
        __syncthreads();
        if (tid < 55) {
            float v = red[tid] + red[55 + tid] + red[110 + tid] + red[165 + tid];
            int k = tid, c1 = 0;
            while (k >= NCLS - c1) { k -= NCLS - c1; c1++; }
            int c2 = c1 + k;
            wtw[c1 * NCLS + c2] = v;
            wtw[c2 * NCLS + c1] = v;
        }
    }
}

// 512 blocks x 256 threads. Block b: samples 4b..4b+3.
// Wave w (0..3) computes partial logits over d-slice [768w, 768w+768).
__global__ __launch_bounds__(256) void main_kernel(const float* __restrict__ data,
                                                   const float* __restrict__ bias,
                                                   const float* __restrict__ ws,
                                                   float* __restrict__ out) {
    const int b   = blockIdx.x;
    const int tid = threadIdx.x;
    const int wv  = tid >> 6;
    const int ln  = tid & 63;

    const float4* wt4 = (const float4*)ws;        // [10][768] float4 view
    const float*  wtw = ws + NCLS * DIMD;

    float acc[4][NCLS];
    #pragma unroll
    for (int s = 0; s < 4; s++)
        #pragma unroll
        for (int c = 0; c < NCLS; c++) acc[s][c] = 0.f;

    const float4* xb = (const float4*)data + (size_t)(4 * b) * 768;
    const int fbase = wv * 192;

    #pragma unroll
    for (int k = 0; k < 3; k++) {
        const int f = fbase + ln + (k << 6);
        float4 xv[4];
        #pragma unroll
        for (int s = 0; s < 4; s++) xv[s] = xb[s * 768 + f];
        #pragma unroll
        for (int c = 0; c < NCLS; c++) {
            float4 wc = wt4[c * 768 + f];
            #pragma unroll
            for (int s = 0; s < 4; s++) {
                acc[s][c] = fmaf(xv[s].x, wc.x, acc[s][c]);
                acc[s][c] = fmaf(xv[s].y, wc.y, acc[s][c]);
                acc[s][c] = fmaf(xv[s].z, wc.z, acc[s][c]);
                acc[s][c] = fmaf(xv[s].w, wc.w, acc[s][c]);
            }
        }
    }

    // 64-lane butterfly: every lane ends with the wave's 40 partial logits
    #pragma unroll
    for (int s = 0; s < 4; s++)
        #pragma unroll
        for (int c = 0; c < NCLS; c++)
            #pragma unroll
            for (int st = 1; st < 64; st <<= 1)
                acc[s][c] += __shfl_xor(acc[s][c], st, 64);

    __shared__ float part[4][40];
    __shared__ float logits_s[40];

    if (ln == 0) {
        #pragma unroll
        for (int s = 0; s < 4; s++)
            #pragma unroll
            for (int c = 0; c < NCLS; c++)
                part[wv][s * NCLS + c] = acc[s][c];
    }
    __syncthreads();
    if (tid < 40) {
        int c = tid % NCLS;
        logits_s[tid] = part[0][tid] + part[1][tid] + part[2][tid] + part[3][tid]
                        + bias[c];
    }
    __syncthreads();

    // ---- epilogue: wave 0, 16 lanes per sample ----
    if (wv == 0) {
        const int g = ln >> 4;   // sample within block
        const int i = ln & 15;   // Atilde row (valid for i<9)

        float l[NCLS];
        #pragma unroll
        for (int c = 0; c < NCLS; c++) l[c] = logits_s[g * NCLS + c];

        float m = l[0];
        #pragma unroll
        for (int c = 1; c < NCLS; c++) m = fmaxf(m, l[c]);
        float e[NCLS], Z = 0.f;
        #pragma unroll
        for (int c = 0; c < NCLS; c++) { e[c] = expf(l[c] - m); Z += e[c]; }
        const float Zinv = 1.f / Z;
        const float sc = 1.f - (float)NCLS * NSTAB;

        float q[NCLS], nc[NCLS], ncsum = 0.f;
        #pragma unroll
        for (int c = 0; c < NCLS; c++) {
            q[c] = e[c] * Zinv;
            float p = fmaf(sc, q[c], NSTAB);
            nc[c] = sqrtf(p);
            ncsum += nc[c];
        }
        const float r  = 1.f - nc[9];
        const float u9 = sc * q[9] / nc[9];

        // select q[i], nc[i] without dynamic register indexing
        float qi = q[0], nci = nc[0];
        #pragma unroll
        for (int j = 1; j < 9; j++) {
            if (i == j) { qi = q[j]; nci = nc[j]; }
        }
        const float ui = sc * qi / nci;
        const float gi = nci * u9 / r;

        // Atilde row i (rho folded in): At[j] = ui*(d_ij - q_j) + gi*(d_9j - q_j)
        float At[NCLS];
        #pragma unroll
        for (int j = 0; j < NCLS; j++) {
            float v = -(ui + gi) * q[j];
            if (j == i) v += ui;
            if (j == 9) v += gi;
            At[j] = v;
        }

        // AK = At . WtW   (WtW uniform-address -> scalar cached loads)
        float AK[NCLS];
        #pragma unroll
        for (int mm = 0; mm < NCLS; mm++) AK[mm] = 0.f;
        #pragma unroll
        for (int k = 0; k < NCLS; k++) {
            float Atk = At[k];
            #pragma unroll
            for (int mm = 0; mm < NCLS; mm++)
                AK[mm] = fmaf(Atk, wtw[k * NCLS + mm], AK[mm]);
        }

        // G row i = AK . Atilde_j (via shfl), accumulate |G| row-sum.
        // G symmetric => norm1 == norminf == max row-sum.
        float rowsum = 0.f;
        #pragma unroll
        for (int j = 0; j < 9; j++) {
            const int src = (g << 4) + j;
            float Gij = 0.f;
            #pragma unroll
            for (int mm = 0; mm < NCLS; mm++) {
                float ajm = __shfl(At[mm], src, 64);
                Gij = fmaf(AK[mm], ajm, Gij);
            }
            rowsum += fabsf(Gij);
        }

        float rs = (i < 9) ? rowsum : 0.f;
        #pragma unroll
        for (int st = 1; st < 16; st <<= 1)
            rs = fmaxf(rs, __shfl_xor(rs, st, 64));

        if (i == 0) {
            float arg = ncsum * 0.31622776601683794f;     // 1/sqrt(10)
            arg = fminf(1.f, fmaxf(-1.f, arg));
            float delta = 2.f * acosf(arg);
            out[4 * b + g] = delta / (EPSI * rs);
        }
    }
}

extern "C" void kernel_launch(void* const* d_in, const int* in_sizes, int n_in,
                              void* d_out, int out_size, void* d_ws, size_t ws_size,
                              hipStream_t stream) {
    const float* data = (const float*)d_in[0];   // [2048,3,32,32] f32
    const float* W    = (const float*)d_in[1];   // [3072,10] f32
    const float* bias = (const float*)d_in[2];   // [10] f32
    float* out = (float*)d_out;                  // [2048] f32
    float* ws  = (float*)d_ws;                   // >= 30820 floats

    prep_kernel<<<33, 256, 0, stream>>>(W, ws);
    main_kernel<<<512, 256, 0, stream>>>(data, bias, ws, out);
}